// Round 1
// baseline (924.004 us; speedup 1.0000x reference)
//
#include <hip/hip_runtime.h>
#include <hip/hip_bf16.h>
#include <math.h>

#define N_NODES 50000
#define N_EDGES 800000
#define IN_FEAT 1000
#define HID 128
#define HEADS 2
#define FOUT 256   /* HEADS*HID */
#define NEG_SLOPE 0.2f
#define EPS 1e-16f

__device__ __forceinline__ float lrelu(float v) { return v > 0.f ? v : NEG_SLOPE * v; }

__device__ __forceinline__ float wave_reduce_sum(float v) {
#pragma unroll
  for (int off = 32; off > 0; off >>= 1) v += __shfl_down(v, off, 64);
  return v;
}

// ---------------- CSR build ----------------
__global__ void hist_kernel(const int* __restrict__ dst, int* __restrict__ counts) {
  int e = blockIdx.x * blockDim.x + threadIdx.x;
  if (e < N_EDGES) atomicAdd(&counts[dst[e]], 1);
}

__global__ void scan_kernel(const int* __restrict__ counts, int* __restrict__ row_start,
                            int* __restrict__ cursor, int n) {
  __shared__ int buf[1024];
  __shared__ int carry;
  const int t = threadIdx.x;
  if (t == 0) carry = 0;
  __syncthreads();
  for (int base = 0; base < n; base += 1024) {
    int i = base + t;
    int v = (i < n) ? counts[i] : 0;
    buf[t] = v;
    __syncthreads();
    for (int off = 1; off < 1024; off <<= 1) {
      int x = (t >= off) ? buf[t - off] : 0;
      __syncthreads();
      buf[t] += x;
      __syncthreads();
    }
    int incl = buf[t];
    int excl_abs = carry + incl - v;  // carry stable until after next barrier
    if (i < n) {
      row_start[i] = excl_abs;
      cursor[i] = excl_abs;
    }
    int ctot = buf[1023];
    __syncthreads();
    if (t == 0) carry += ctot;
    __syncthreads();
  }
  if (t == 0) row_start[n] = carry;
}

__global__ void scatter_kernel(const int* __restrict__ src, const int* __restrict__ dst,
                               int* __restrict__ cursor, int* __restrict__ csr_src) {
  int e = blockIdx.x * blockDim.x + threadIdx.x;
  if (e < N_EDGES) {
    int pos = atomicAdd(&cursor[dst[e]], 1);
    csr_src[pos] = src[e];
  }
}

// ---------------- GEMM: h1 = x @ W1   [N,1000] x [1000,256] ----------------
#define BM 64
#define BK 8

__global__ __launch_bounds__(256) void gemm1_kernel(const float* __restrict__ A,
                                                    const float* __restrict__ B,
                                                    float* __restrict__ C) {
  __shared__ float As[BK][BM];
  __shared__ float Bs[BK][FOUT];
  const int t = threadIdx.x;
  const int row0 = blockIdx.x * BM;
  const int tm = t >> 4;   // 0..15
  const int tn = t & 15;   // 0..15
  const int m0 = tm * 4;
  const int n0 = tn * 4;   // cols handled: n0 + 64*j + {0..3}
  float acc[4][16];
#pragma unroll
  for (int i = 0; i < 4; ++i)
#pragma unroll
    for (int j = 0; j < 16; ++j) acc[i][j] = 0.f;

  const int la_row = t >> 1;        // 0..127
  const int la_k = (t & 1) * 4;     // 0 or 4
  const int arow = min(row0 + la_row, N_NODES - 1);
  const float* Aptr = A + (size_t)arow * IN_FEAT + la_k;

  for (int k0 = 0; k0 < IN_FEAT; k0 += BK) {
    if (t < 128) {
      float4 a4 = *(const float4*)(Aptr + k0);
      As[la_k + 0][la_row] = a4.x;
      As[la_k + 1][la_row] = a4.y;
      As[la_k + 2][la_row] = a4.z;
      As[la_k + 3][la_row] = a4.w;
    }
    {
      int bk = t >> 6, bn = (t & 63) * 4;
      *(float4*)&Bs[bk][bn] = *(const float4*)(B + (size_t)(k0 + bk) * FOUT + bn);
      int t2 = t + 256;
      int bk2 = t2 >> 6, bn2 = (t2 & 63) * 4;
      *(float4*)&Bs[bk2][bn2] = *(const float4*)(B + (size_t)(k0 + bk2) * FOUT + bn2);
    }
    __syncthreads();
#pragma unroll
    for (int k = 0; k < BK; ++k) {
      float4 a4 = *(const float4*)&As[k][m0];
      float av[4] = {a4.x, a4.y, a4.z, a4.w};
      float bv[16];
#pragma unroll
      for (int j = 0; j < 4; ++j) {
        float4 b4 = *(const float4*)&Bs[k][n0 + 64 * j];
        bv[4 * j + 0] = b4.x;
        bv[4 * j + 1] = b4.y;
        bv[4 * j + 2] = b4.z;
        bv[4 * j + 3] = b4.w;
      }
#pragma unroll
      for (int i = 0; i < 4; ++i)
#pragma unroll
        for (int j = 0; j < 16; ++j) acc[i][j] = fmaf(av[i], bv[j], acc[i][j]);
    }
    __syncthreads();
  }
#pragma unroll
  for (int i = 0; i < 4; ++i) {
    int r = row0 + m0 + i;
    if (r < N_NODES) {
#pragma unroll
      for (int j = 0; j < 4; ++j) {
        float4 o = make_float4(acc[i][4 * j + 0], acc[i][4 * j + 1], acc[i][4 * j + 2],
                               acc[i][4 * j + 3]);
        *(float4*)(C + (size_t)r * FOUT + n0 + 64 * j) = o;
      }
    }
  }
}

// ---------------- attention logits per node: a_src/a_dst [N,2] ----------------
__global__ __launch_bounds__(64) void att1_kernel(const float* __restrict__ h1,
                                                  const float* __restrict__ as,
                                                  const float* __restrict__ ad,
                                                  float* __restrict__ asrc,
                                                  float* __restrict__ adst) {
  const int n = blockIdx.x;
  const int lane = threadIdx.x;
  const float* hr = h1 + (size_t)n * FOUT;
  float h0 = hr[lane], h1v = hr[lane + 64], h2v = hr[lane + 128], h3v = hr[lane + 192];
  float ps0 = h0 * as[lane] + h1v * as[lane + 64];
  float ps1 = h2v * as[lane + 128] + h3v * as[lane + 192];
  float pd0 = h0 * ad[lane] + h1v * ad[lane + 64];
  float pd1 = h2v * ad[lane + 128] + h3v * ad[lane + 192];
  ps0 = wave_reduce_sum(ps0);
  ps1 = wave_reduce_sum(ps1);
  pd0 = wave_reduce_sum(pd0);
  pd1 = wave_reduce_sum(pd1);
  if (lane == 0) {
    asrc[2 * n + 0] = ps0;
    asrc[2 * n + 1] = ps1;
    adst[2 * n + 0] = pd0;
    adst[2 * n + 1] = pd1;
  }
}

// ---------------- layer-1 aggregation + bias + relu + W2 dot -> z[n] ----------------
__global__ __launch_bounds__(64) void agg1_kernel(
    const float* __restrict__ h1, const float* __restrict__ asrc,
    const float* __restrict__ adst, const int* __restrict__ row_start,
    const int* __restrict__ csr_src, const float* __restrict__ b1,
    const float* __restrict__ W2, float* __restrict__ z) {
  const int n = blockIdx.x;
  const int lane = threadIdx.x;
  const float ad0 = adst[2 * n], ad1 = adst[2 * n + 1];
  const int jb = row_start[n], je = row_start[n + 1];
  float acc0 = 0.f, acc1 = 0.f, acc2 = 0.f, acc3 = 0.f;
  float m0 = -INFINITY, m1 = -INFINITY, s0 = 0.f, s1 = 0.f;
  for (int j = jb; j < je; ++j) {
    const int sr = csr_src[j];
    float e0 = lrelu(asrc[2 * sr] + ad0);
    float e1 = lrelu(asrc[2 * sr + 1] + ad1);
    float p0, p1;
    if (e0 > m0) {  // uniform branch: e0 identical across the wave
      float f = __expf(m0 - e0);  // exp(-inf)=0 handles the first edge
      s0 *= f; acc0 *= f; acc1 *= f; m0 = e0; p0 = 1.f;
    } else {
      p0 = __expf(e0 - m0);
    }
    if (e1 > m1) {
      float f = __expf(m1 - e1);
      s1 *= f; acc2 *= f; acc3 *= f; m1 = e1; p1 = 1.f;
    } else {
      p1 = __expf(e1 - m1);
    }
    s0 += p0;
    s1 += p1;
    const float* hr = h1 + (size_t)sr * FOUT;
    acc0 = fmaf(p0, hr[lane], acc0);
    acc1 = fmaf(p0, hr[lane + 64], acc1);
    acc2 = fmaf(p1, hr[lane + 128], acc2);
    acc3 = fmaf(p1, hr[lane + 192], acc3);
  }
  float inv0 = 1.f / (s0 + EPS), inv1 = 1.f / (s1 + EPS);
  float r0 = fmaxf(acc0 * inv0 + b1[lane], 0.f);
  float r1 = fmaxf(acc1 * inv0 + b1[lane + 64], 0.f);
  float r2 = fmaxf(acc2 * inv1 + b1[lane + 128], 0.f);
  float r3 = fmaxf(acc3 * inv1 + b1[lane + 192], 0.f);
  float part = r0 * W2[lane] + r1 * W2[lane + 64] + r2 * W2[lane + 128] + r3 * W2[lane + 192];
  part = wave_reduce_sum(part);
  if (lane == 0) z[n] = part;
}

// ---------------- layer-2 GAT (scalar features) ----------------
__global__ void agg2_kernel(const float* __restrict__ z, const int* __restrict__ row_start,
                            const int* __restrict__ csr_src, const float* __restrict__ as2p,
                            const float* __restrict__ ad2p, const float* __restrict__ b2p,
                            float* __restrict__ out2) {
  int n = blockIdx.x * blockDim.x + threadIdx.x;
  if (n >= N_NODES) return;
  const float as2 = as2p[0], ad2 = ad2p[0], b2 = b2p[0];
  const float adz = z[n] * ad2;
  const int jb = row_start[n], je = row_start[n + 1];
  float m = -INFINITY, s = 0.f, num = 0.f;
  for (int j = jb; j < je; ++j) {
    float zs = z[csr_src[j]];
    float e = lrelu(zs * as2 + adz);
    float p;
    if (e > m) {
      float f = __expf(m - e);
      s *= f; num *= f; m = e; p = 1.f;
    } else {
      p = __expf(e - m);
    }
    s += p;
    num = fmaf(p, zs, num);
  }
  out2[n] = num / (s + EPS) + b2;
}

__global__ void readout_kernel(const float* __restrict__ out2, const int* __restrict__ ridx,
                               float* __restrict__ out, int n) {
  int i = blockIdx.x * blockDim.x + threadIdx.x;
  if (i < n) out[i] = out2[ridx[i]];
}

extern "C" void kernel_launch(void* const* d_in, const int* in_sizes, int n_in,
                              void* d_out, int out_size, void* d_ws, size_t ws_size,
                              hipStream_t stream) {
  const float* x   = (const float*)d_in[0];
  const int* ei    = (const int*)d_in[1];
  const int* ridx  = (const int*)d_in[2];
  const float* W1  = (const float*)d_in[3];
  const float* as1 = (const float*)d_in[4];
  const float* ad1 = (const float*)d_in[5];
  const float* b1  = (const float*)d_in[6];
  const float* W2  = (const float*)d_in[7];
  const float* as2 = (const float*)d_in[8];
  const float* ad2 = (const float*)d_in[9];
  const float* b2  = (const float*)d_in[10];
  float* out = (float*)d_out;

  char* ws = (char*)d_ws;
  size_t off = 0;
  auto alloc = [&](size_t bytes) -> void* {
    void* p = ws + off;
    off += (bytes + 255) & ~(size_t)255;
    return p;
  };
  float* h1   = (float*)alloc((size_t)N_NODES * FOUT * 4);
  float* asrc = (float*)alloc((size_t)N_NODES * 2 * 4);
  float* adst = (float*)alloc((size_t)N_NODES * 2 * 4);
  float* z    = (float*)alloc((size_t)N_NODES * 4);
  float* out2 = (float*)alloc((size_t)N_NODES * 4);
  int* counts = (int*)alloc((size_t)N_NODES * 4);
  int* rowst  = (int*)alloc((size_t)(N_NODES + 1) * 4);
  int* cursor = (int*)alloc((size_t)N_NODES * 4);
  int* csr    = (int*)alloc((size_t)N_EDGES * 4);

  const int* src = ei;
  const int* dst = ei + N_EDGES;

  hipMemsetAsync(counts, 0, (size_t)N_NODES * 4, stream);
  hist_kernel<<<(N_EDGES + 255) / 256, 256, 0, stream>>>(dst, counts);
  scan_kernel<<<1, 1024, 0, stream>>>(counts, rowst, cursor, N_NODES);
  scatter_kernel<<<(N_EDGES + 255) / 256, 256, 0, stream>>>(src, dst, cursor, csr);
  gemm1_kernel<<<(N_NODES + BM - 1) / BM, 256, 0, stream>>>(x, W1, h1);
  att1_kernel<<<N_NODES, 64, 0, stream>>>(h1, as1, ad1, asrc, adst);
  agg1_kernel<<<N_NODES, 64, 0, stream>>>(h1, asrc, adst, rowst, csr, b1, W2, z);
  agg2_kernel<<<(N_NODES + 255) / 256, 256, 0, stream>>>(z, rowst, csr, as2, ad2, b2, out2);
  readout_kernel<<<4, 256, 0, stream>>>(out2, ridx, out, out_size);
}

// Round 2
// 738.439 us; speedup vs baseline: 1.2513x; 1.2513x over previous
//
#include <hip/hip_runtime.h>
#include <hip/hip_bf16.h>
#include <math.h>

#define N_NODES 50000
#define N_EDGES 800000
#define IN_FEAT 1000
#define HID 128
#define HEADS 2
#define FOUT 256   /* HEADS*HID */
#define NEG_SLOPE 0.2f
#define EPS 1e-16f

#define KPAD 1024
#define MPAD 50048          /* 391*128 */
#define GEMM_NWG 782        /* 391 row-panels x 2 col-blocks */

typedef __bf16 bf16x8 __attribute__((ext_vector_type(8)));
typedef float f32x4 __attribute__((ext_vector_type(4)));

__device__ __forceinline__ float lrelu(float v) { return v > 0.f ? v : NEG_SLOPE * v; }

__device__ __forceinline__ float wave_reduce_sum(float v) {
#pragma unroll
  for (int off = 32; off > 0; off >>= 1) v += __shfl_down(v, off, 64);
  return v;
}

__device__ __forceinline__ ushort bf16rn(float v) {
  union { float f; unsigned u; } a; a.f = v;
  unsigned r = a.u + 0x7FFFu + ((a.u >> 16) & 1u);
  return (ushort)(r >> 16);
}
__device__ __forceinline__ void bf16split(float v, ushort& h, ushort& l) {
  h = bf16rn(v);
  union { float f; unsigned u; } b; b.u = ((unsigned)h) << 16;
  l = bf16rn(v - b.f);
}

__device__ __forceinline__ void gload_lds16(const void* g, void* l) {
  __builtin_amdgcn_global_load_lds((const __attribute__((address_space(1))) void*)g,
                                   (__attribute__((address_space(3))) void*)l, 16, 0, 0);
}

// ---------------- CSR build ----------------
__global__ void hist_kernel(const int* __restrict__ dst, int* __restrict__ counts) {
  int e = blockIdx.x * blockDim.x + threadIdx.x;
  if (e < N_EDGES) atomicAdd(&counts[dst[e]], 1);
}

__global__ void scan_kernel(const int* __restrict__ counts, int* __restrict__ row_start,
                            int* __restrict__ cursor, int n) {
  __shared__ int buf[1024];
  __shared__ int carry;
  const int t = threadIdx.x;
  if (t == 0) carry = 0;
  __syncthreads();
  for (int base = 0; base < n; base += 1024) {
    int i = base + t;
    int v = (i < n) ? counts[i] : 0;
    buf[t] = v;
    __syncthreads();
    for (int off = 1; off < 1024; off <<= 1) {
      int x = (t >= off) ? buf[t - off] : 0;
      __syncthreads();
      buf[t] += x;
      __syncthreads();
    }
    int incl = buf[t];
    int excl_abs = carry + incl - v;
    if (i < n) {
      row_start[i] = excl_abs;
      cursor[i] = excl_abs;
    }
    int ctot = buf[1023];
    __syncthreads();
    if (t == 0) carry += ctot;
    __syncthreads();
  }
  if (t == 0) row_start[n] = carry;
}

__global__ void scatter_kernel(const int* __restrict__ src, const int* __restrict__ dst,
                               int* __restrict__ cursor, int* __restrict__ csr_src) {
  int e = blockIdx.x * blockDim.x + threadIdx.x;
  if (e < N_EDGES) {
    int pos = atomicAdd(&cursor[dst[e]], 1);
    csr_src[pos] = src[e];
  }
}

// ---------------- bf16 hi/lo conversion ----------------
// A: x[50000][1000] f32 -> Ahi/Alo [MPAD][KPAD] bf16 (zero-padded)
__global__ __launch_bounds__(256) void cvtA_kernel(const float* __restrict__ x,
                                                   ushort* __restrict__ hi,
                                                   ushort* __restrict__ lo) {
  const int n = blockIdx.x;          // 0..MPAD-1
  const int k4 = threadIdx.x << 2;   // 0..1020
  float4 v = make_float4(0.f, 0.f, 0.f, 0.f);
  if (n < N_NODES && k4 < IN_FEAT) v = *(const float4*)(x + (size_t)n * IN_FEAT + k4);
  ushort4 h, l;
  bf16split(v.x, h.x, l.x);
  bf16split(v.y, h.y, l.y);
  bf16split(v.z, h.z, l.z);
  bf16split(v.w, h.w, l.w);
  *(ushort4*)(hi + (size_t)n * KPAD + k4) = h;
  *(ushort4*)(lo + (size_t)n * KPAD + k4) = l;
}

// B: W1[1000][256] f32 -> Bt hi/lo [256][KPAD] bf16 (transposed, zero-padded)
__global__ __launch_bounds__(256) void cvtB_kernel(const float* __restrict__ B,
                                                   ushort* __restrict__ thi,
                                                   ushort* __restrict__ tlo) {
  int i = blockIdx.x * 256 + threadIdx.x;   // 0..65535
  int nn = i >> 8;
  int k4 = (i & 255) << 2;
  ushort4 h, l;
#pragma unroll
  for (int j = 0; j < 4; ++j) {
    int k = k4 + j;
    float v = (k < IN_FEAT) ? B[(size_t)k * FOUT + nn] : 0.f;
    ushort hh, ll;
    bf16split(v, hh, ll);
    ((ushort*)&h)[j] = hh;
    ((ushort*)&l)[j] = ll;
  }
  *(ushort4*)(thi + (size_t)nn * KPAD + k4) = h;
  *(ushort4*)(tlo + (size_t)nn * KPAD + k4) = l;
}

// ---------------- split-bf16 MFMA GEMM: h1 = x @ W1 ----------------
// A hi/lo [MPAD][KPAD], Bt hi/lo [256][KPAD]; C [N_NODES][256] f32
// BM=128 rows x BN=128 cols per block, BK=64, 4 waves (64x64 wave tile)
__global__ __launch_bounds__(256, 2) void gemm_mfma_kernel(
    const ushort* __restrict__ Ahi, const ushort* __restrict__ Alo,
    const ushort* __restrict__ Bhi, const ushort* __restrict__ Blo,
    float* __restrict__ C) {
  __shared__ ushort lAhi[128 * 64];
  __shared__ ushort lAlo[128 * 64];
  __shared__ ushort lBhi[128 * 64];
  __shared__ ushort lBlo[128 * 64];

  // bijective XCD swizzle (m204): keep the 2 col-blocks of a row-panel on one XCD
  const int orig = blockIdx.x;
  const int q = GEMM_NWG >> 3, r = GEMM_NWG & 7;
  const int xcd = orig & 7, idx = orig >> 3;
  const int lin = (xcd < r) ? xcd * (q + 1) + idx : r * (q + 1) + (xcd - r) * q + idx;
  const int brow = (lin >> 1) * 128;
  const int bcol = (lin & 1) * 128;

  const int t = threadIdx.x;
  const int lane = t & 63, wid = t >> 6;
  const int wr = wid >> 1, wc = wid & 1;
  const int fr = lane & 15, g = lane >> 4;

  auto stage = [&](int ks) {
    const int k0b = ks * 128;  // byte offset into 2048-byte rows
#pragma unroll
    for (int i = 0; i < 4; ++i) {
      int u = i * 256 + t;        // 16B-chunk id, 0..1023
      int row = u >> 3;           // 0..127
      int inner = (u & 7) * 16;   // byte within 128B row-chunk
      int soff = inner ^ ((row & 7) << 4);  // inverse-swizzled source
      size_t aoff = (size_t)(brow + row) * (KPAD * 2) + k0b + soff;
      size_t boff = (size_t)(bcol + row) * (KPAD * 2) + k0b + soff;
      int loff = u * 16;
      gload_lds16((const char*)Ahi + aoff, (char*)lAhi + loff);
      gload_lds16((const char*)Alo + aoff, (char*)lAlo + loff);
      gload_lds16((const char*)Bhi + boff, (char*)lBhi + loff);
      gload_lds16((const char*)Blo + boff, (char*)lBlo + loff);
    }
  };

  f32x4 acc[4][4];
  const f32x4 z4 = {0.f, 0.f, 0.f, 0.f};
#pragma unroll
  for (int m = 0; m < 4; ++m)
#pragma unroll
    for (int n = 0; n < 4; ++n) acc[m][n] = z4;

  stage(0);
  const int NK = KPAD / 64;  // 16
  for (int ks = 0; ks < NK; ++ks) {
    __syncthreads();  // compiler drains vmcnt before barrier -> LDS ready
#pragma unroll
    for (int h = 0; h < 2; ++h) {
      bf16x8 ah[4], al[4], bh[4], bl[4];
#pragma unroll
      for (int m = 0; m < 4; ++m) {
        int row = wr * 64 + m * 16 + fr;
        int off = row * 128 + ((h * 64 + g * 16) ^ ((row & 7) << 4));
        ah[m] = *(const bf16x8*)((const char*)lAhi + off);
        al[m] = *(const bf16x8*)((const char*)lAlo + off);
      }
#pragma unroll
      for (int n = 0; n < 4; ++n) {
        int row = wc * 64 + n * 16 + fr;
        int off = row * 128 + ((h * 64 + g * 16) ^ ((row & 7) << 4));
        bh[n] = *(const bf16x8*)((const char*)lBhi + off);
        bl[n] = *(const bf16x8*)((const char*)lBlo + off);
      }
#pragma unroll
      for (int m = 0; m < 4; ++m)
#pragma unroll
        for (int n = 0; n < 4; ++n) {
          acc[m][n] = __builtin_amdgcn_mfma_f32_16x16x32_bf16(ah[m], bh[n], acc[m][n], 0, 0, 0);
          acc[m][n] = __builtin_amdgcn_mfma_f32_16x16x32_bf16(ah[m], bl[n], acc[m][n], 0, 0, 0);
          acc[m][n] = __builtin_amdgcn_mfma_f32_16x16x32_bf16(al[m], bh[n], acc[m][n], 0, 0, 0);
        }
    }
    __syncthreads();  // all waves done reading this tile
    if (ks + 1 < NK) stage(ks + 1);
  }

  // C/D layout: col = lane&15, row = (lane>>4)*4 + reg  [m89-verified]
#pragma unroll
  for (int m = 0; m < 4; ++m) {
    int growbase = brow + wr * 64 + m * 16 + g * 4;
#pragma unroll
    for (int n = 0; n < 4; ++n) {
      int gcol = bcol + wc * 64 + n * 16 + fr;
#pragma unroll
      for (int rr = 0; rr < 4; ++rr) {
        int grow = growbase + rr;
        if (grow < N_NODES) C[(size_t)grow * FOUT + gcol] = acc[m][n][rr];
      }
    }
  }
}

// ---------------- f32 fallback GEMM (round-1, known-correct) ----------------
#define BM 64
#define BK 8
__global__ __launch_bounds__(256) void gemm1_kernel(const float* __restrict__ A,
                                                    const float* __restrict__ B,
                                                    float* __restrict__ C) {
  __shared__ float As[BK][BM];
  __shared__ float Bs[BK][FOUT];
  const int t = threadIdx.x;
  const int row0 = blockIdx.x * BM;
  const int tm = t >> 4;
  const int tn = t & 15;
  const int m0 = tm * 4;
  const int n0 = tn * 4;
  float acc[4][16];
#pragma unroll
  for (int i = 0; i < 4; ++i)
#pragma unroll
    for (int j = 0; j < 16; ++j) acc[i][j] = 0.f;

  const int la_row = t >> 1;
  const int la_k = (t & 1) * 4;
  const int arow = min(row0 + la_row, N_NODES - 1);
  const float* Aptr = A + (size_t)arow * IN_FEAT + la_k;

  for (int k0 = 0; k0 < IN_FEAT; k0 += BK) {
    if (t < 128) {
      float4 a4 = *(const float4*)(Aptr + k0);
      As[la_k + 0][la_row] = a4.x;
      As[la_k + 1][la_row] = a4.y;
      As[la_k + 2][la_row] = a4.z;
      As[la_k + 3][la_row] = a4.w;
    }
    {
      int bk = t >> 6, bn = (t & 63) * 4;
      *(float4*)&Bs[bk][bn] = *(const float4*)(B + (size_t)(k0 + bk) * FOUT + bn);
      int t2 = t + 256;
      int bk2 = t2 >> 6, bn2 = (t2 & 63) * 4;
      *(float4*)&Bs[bk2][bn2] = *(const float4*)(B + (size_t)(k0 + bk2) * FOUT + bn2);
    }
    __syncthreads();
#pragma unroll
    for (int k = 0; k < BK; ++k) {
      float4 a4 = *(const float4*)&As[k][m0];
      float av[4] = {a4.x, a4.y, a4.z, a4.w};
      float bv[16];
#pragma unroll
      for (int j = 0; j < 4; ++j) {
        float4 b4 = *(const float4*)&Bs[k][n0 + 64 * j];
        bv[4 * j + 0] = b4.x;
        bv[4 * j + 1] = b4.y;
        bv[4 * j + 2] = b4.z;
        bv[4 * j + 3] = b4.w;
      }
#pragma unroll
      for (int i = 0; i < 4; ++i)
#pragma unroll
        for (int j = 0; j < 16; ++j) acc[i][j] = fmaf(av[i], bv[j], acc[i][j]);
    }
    __syncthreads();
  }
#pragma unroll
  for (int i = 0; i < 4; ++i) {
    int r = row0 + m0 + i;
    if (r < N_NODES) {
#pragma unroll
      for (int j = 0; j < 4; ++j) {
        float4 o = make_float4(acc[i][4 * j + 0], acc[i][4 * j + 1], acc[i][4 * j + 2],
                               acc[i][4 * j + 3]);
        *(float4*)(C + (size_t)r * FOUT + n0 + 64 * j) = o;
      }
    }
  }
}

// ---------------- attention logits per node ----------------
__global__ __launch_bounds__(64) void att1_kernel(const float* __restrict__ h1,
                                                  const float* __restrict__ as,
                                                  const float* __restrict__ ad,
                                                  float* __restrict__ asrc,
                                                  float* __restrict__ adst) {
  const int n = blockIdx.x;
  const int lane = threadIdx.x;
  const float* hr = h1 + (size_t)n * FOUT;
  float4 hv = *(const float4*)(hr + 4 * lane);
  float4 sv = *(const float4*)(as + 4 * lane);
  float4 dv = *(const float4*)(ad + 4 * lane);
  float ps = hv.x * sv.x + hv.y * sv.y + hv.z * sv.z + hv.w * sv.w;
  float pd = hv.x * dv.x + hv.y * dv.y + hv.z * dv.z + hv.w * dv.w;
#pragma unroll
  for (int off = 16; off > 0; off >>= 1) {  // reduce within each 32-lane half
    ps += __shfl_xor(ps, off, 64);
    pd += __shfl_xor(pd, off, 64);
  }
  if ((lane & 31) == 0) {
    int hh = lane >> 5;
    asrc[2 * n + hh] = ps;
    adst[2 * n + hh] = pd;
  }
}

// ---------------- layer-1 aggregation + bias + relu + W2 dot -> z[n] ----------------
__global__ __launch_bounds__(64) void agg1_kernel(
    const float* __restrict__ h1, const float* __restrict__ asrc,
    const float* __restrict__ adst, const int* __restrict__ row_start,
    const int* __restrict__ csr_src, const float* __restrict__ b1,
    const float* __restrict__ W2, float* __restrict__ z) {
  const int n = blockIdx.x;
  const int lane = threadIdx.x;
  const bool head0 = lane < 32;
  const float ad0 = adst[2 * n], ad1 = adst[2 * n + 1];
  const int jb = row_start[n], je = row_start[n + 1];
  float ax = 0.f, ay = 0.f, az = 0.f, aw = 0.f;
  float m0 = -INFINITY, m1 = -INFINITY, s0 = 0.f, s1 = 0.f;
  for (int j = jb; j < je; ++j) {
    const int sr = csr_src[j];
    float e0 = lrelu(asrc[2 * sr] + ad0);
    float e1 = lrelu(asrc[2 * sr + 1] + ad1);
    float m0n = fmaxf(m0, e0), m1n = fmaxf(m1, e1);
    float f0 = __expf(m0 - m0n), f1 = __expf(m1 - m1n);
    float p0 = __expf(e0 - m0n), p1 = __expf(e1 - m1n);
    s0 = s0 * f0 + p0;
    s1 = s1 * f1 + p1;
    m0 = m0n;
    m1 = m1n;
    float f = head0 ? f0 : f1;
    float p = head0 ? p0 : p1;
    float4 hv = *(const float4*)(h1 + (size_t)sr * FOUT + 4 * lane);
    ax = fmaf(ax, f, p * hv.x);
    ay = fmaf(ay, f, p * hv.y);
    az = fmaf(az, f, p * hv.z);
    aw = fmaf(aw, f, p * hv.w);
  }
  float inv = head0 ? 1.f / (s0 + EPS) : 1.f / (s1 + EPS);
  float4 bv = *(const float4*)(b1 + 4 * lane);
  float4 wv = *(const float4*)(W2 + 4 * lane);
  float r0 = fmaxf(fmaf(ax, inv, bv.x), 0.f);
  float r1 = fmaxf(fmaf(ay, inv, bv.y), 0.f);
  float r2 = fmaxf(fmaf(az, inv, bv.z), 0.f);
  float r3 = fmaxf(fmaf(aw, inv, bv.w), 0.f);
  float part = r0 * wv.x + r1 * wv.y + r2 * wv.z + r3 * wv.w;
  part = wave_reduce_sum(part);
  if (lane == 0) z[n] = part;
}

// ---------------- layer-2 GAT (scalar features) ----------------
__global__ void agg2_kernel(const float* __restrict__ z, const int* __restrict__ row_start,
                            const int* __restrict__ csr_src, const float* __restrict__ as2p,
                            const float* __restrict__ ad2p, const float* __restrict__ b2p,
                            float* __restrict__ out2) {
  int n = blockIdx.x * blockDim.x + threadIdx.x;
  if (n >= N_NODES) return;
  const float as2 = as2p[0], ad2 = ad2p[0], b2 = b2p[0];
  const float adz = z[n] * ad2;
  const int jb = row_start[n], je = row_start[n + 1];
  float m = -INFINITY, s = 0.f, num = 0.f;
  for (int j = jb; j < je; ++j) {
    float zs = z[csr_src[j]];
    float e = lrelu(zs * as2 + adz);
    float mn = fmaxf(m, e);
    float f = __expf(m - mn);
    float p = __expf(e - mn);
    s = s * f + p;
    num = fmaf(num, f, p * zs);
    m = mn;
  }
  out2[n] = num / (s + EPS) + b2;
}

__global__ void readout_kernel(const float* __restrict__ out2, const int* __restrict__ ridx,
                               float* __restrict__ out, int n) {
  int i = blockIdx.x * blockDim.x + threadIdx.x;
  if (i < n) out[i] = out2[ridx[i]];
}

extern "C" void kernel_launch(void* const* d_in, const int* in_sizes, int n_in,
                              void* d_out, int out_size, void* d_ws, size_t ws_size,
                              hipStream_t stream) {
  const float* x   = (const float*)d_in[0];
  const int* ei    = (const int*)d_in[1];
  const int* ridx  = (const int*)d_in[2];
  const float* W1  = (const float*)d_in[3];
  const float* as1 = (const float*)d_in[4];
  const float* ad1 = (const float*)d_in[5];
  const float* b1  = (const float*)d_in[6];
  const float* W2  = (const float*)d_in[7];
  const float* as2 = (const float*)d_in[8];
  const float* ad2 = (const float*)d_in[9];
  const float* b2  = (const float*)d_in[10];
  float* out = (float*)d_out;

  char* ws = (char*)d_ws;
  size_t off = 0;
  auto alloc = [&](size_t bytes) -> void* {
    void* p = ws + off;
    off += (bytes + 255) & ~(size_t)255;
    return p;
  };
  // common
  float* h1   = (float*)alloc((size_t)N_NODES * FOUT * 4);
  float* asrc = (float*)alloc((size_t)N_NODES * 2 * 4);
  float* adst = (float*)alloc((size_t)N_NODES * 2 * 4);
  float* z    = (float*)alloc((size_t)N_NODES * 4);
  float* out2 = (float*)alloc((size_t)N_NODES * 4);
  int* counts = (int*)alloc((size_t)N_NODES * 4);
  int* rowst  = (int*)alloc((size_t)(N_NODES + 1) * 4);
  int* cursor = (int*)alloc((size_t)N_NODES * 4);
  int* csr    = (int*)alloc((size_t)N_EDGES * 4);
  // mfma extras
  size_t common_end = off;
  ushort* Ahi = (ushort*)alloc((size_t)MPAD * KPAD * 2);
  ushort* Alo = (ushort*)alloc((size_t)MPAD * KPAD * 2);
  ushort* Bhi = (ushort*)alloc((size_t)FOUT * KPAD * 2);
  ushort* Blo = (ushort*)alloc((size_t)FOUT * KPAD * 2);
  const bool use_mfma = (ws_size >= off);
  (void)common_end;

  const int* src = ei;
  const int* dst = ei + N_EDGES;

  hipMemsetAsync(counts, 0, (size_t)N_NODES * 4, stream);
  hist_kernel<<<(N_EDGES + 255) / 256, 256, 0, stream>>>(dst, counts);
  scan_kernel<<<1, 1024, 0, stream>>>(counts, rowst, cursor, N_NODES);
  scatter_kernel<<<(N_EDGES + 255) / 256, 256, 0, stream>>>(src, dst, cursor, csr);

  if (use_mfma) {
    cvtB_kernel<<<256, 256, 0, stream>>>(W1, Bhi, Blo);
    cvtA_kernel<<<MPAD, 256, 0, stream>>>(x, Ahi, Alo);
    gemm_mfma_kernel<<<GEMM_NWG, 256, 0, stream>>>(Ahi, Alo, Bhi, Blo, h1);
  } else {
    gemm1_kernel<<<(N_NODES + BM - 1) / BM, 256, 0, stream>>>(x, W1, h1);
  }

  att1_kernel<<<N_NODES, 64, 0, stream>>>(h1, as1, ad1, asrc, adst);
  agg1_kernel<<<N_NODES, 64, 0, stream>>>(h1, asrc, adst, rowst, csr, b1, W2, z);
  agg2_kernel<<<(N_NODES + 255) / 256, 256, 0, stream>>>(z, rowst, csr, as2, ad2, b2, out2);
  readout_kernel<<<4, 256, 0, stream>>>(out2, ridx, out, out_size);
}

// Round 3
// 574.640 us; speedup vs baseline: 1.6080x; 1.2850x over previous
//
#include <hip/hip_runtime.h>
#include <hip/hip_bf16.h>
#include <math.h>

#define N_NODES 50000
#define N_EDGES 800000
#define IN_FEAT 1000
#define HID 128
#define HEADS 2
#define FOUT 256   /* HEADS*HID */
#define NEG_SLOPE 0.2f
#define EPS 1e-16f

#define KPAD 1024
#define GEMM_NWG 782        /* 391 row-panels x 2 col-blocks */

typedef __bf16 bf16x8 __attribute__((ext_vector_type(8)));
typedef float f32x4 __attribute__((ext_vector_type(4)));

__device__ __forceinline__ float lrelu(float v) { return v > 0.f ? v : NEG_SLOPE * v; }

__device__ __forceinline__ ushort bf16rn(float v) {
  union { float f; unsigned u; } a; a.f = v;
  unsigned r = a.u + 0x7FFFu + ((a.u >> 16) & 1u);
  return (ushort)(r >> 16);
}
__device__ __forceinline__ void bf16split(float v, ushort& h, ushort& l) {
  h = bf16rn(v);
  union { float f; unsigned u; } b; b.u = ((unsigned)h) << 16;
  l = bf16rn(v - b.f);
}

__device__ __forceinline__ void gload_lds16(const void* g, void* l) {
  __builtin_amdgcn_global_load_lds((const __attribute__((address_space(1))) void*)g,
                                   (__attribute__((address_space(3))) void*)l, 16, 0, 0);
}

// ---------------- CSR build ----------------
__global__ void hist_kernel(const int* __restrict__ dst, int* __restrict__ counts) {
  int e = blockIdx.x * blockDim.x + threadIdx.x;
  if (e < N_EDGES) atomicAdd(&counts[dst[e]], 1);
}

// partial inclusive scan per 1024-block
__global__ __launch_bounds__(1024) void scan1_kernel(const int* __restrict__ counts,
                                                     int* __restrict__ iscan,
                                                     int* __restrict__ bsum) {
  __shared__ int buf[1024];
  const int t = threadIdx.x;
  const int i = blockIdx.x * 1024 + t;
  int v = (i < N_NODES) ? counts[i] : 0;
  buf[t] = v;
  __syncthreads();
#pragma unroll
  for (int off = 1; off < 1024; off <<= 1) {
    int x = (t >= off) ? buf[t - off] : 0;
    __syncthreads();
    buf[t] += x;
    __syncthreads();
  }
  if (i < N_NODES) iscan[i] = buf[t];
  if (t == 1023) bsum[blockIdx.x] = buf[1023];
}

// scan 49 block sums in one wave
__global__ __launch_bounds__(64) void scan2_kernel(const int* __restrict__ bsum,
                                                   int* __restrict__ boff,
                                                   int* __restrict__ row_start, int nblk) {
  const int t = threadIdx.x;
  int v = (t < nblk) ? bsum[t] : 0;
  int s = v;
#pragma unroll
  for (int off = 1; off < 64; off <<= 1) {
    int y = __shfl_up(s, off, 64);
    if (t >= off) s += y;
  }
  if (t < nblk) boff[t] = s - v;
  if (t == nblk - 1) row_start[N_NODES] = s;
}

__global__ void scan3_kernel(const int* __restrict__ iscan, const int* __restrict__ counts,
                             const int* __restrict__ boff, int* __restrict__ row_start,
                             int* __restrict__ cursor) {
  int i = blockIdx.x * blockDim.x + threadIdx.x;
  if (i < N_NODES) {
    int rs = boff[i >> 10] + iscan[i] - counts[i];
    row_start[i] = rs;
    cursor[i] = rs;
  }
}

__global__ void scatter_kernel(const int* __restrict__ src, const int* __restrict__ dst,
                               int* __restrict__ cursor, int* __restrict__ csr_src) {
  int e = blockIdx.x * blockDim.x + threadIdx.x;
  if (e < N_EDGES) {
    int pos = atomicAdd(&cursor[dst[e]], 1);
    csr_src[pos] = src[e];
  }
}

// B: W1[1000][256] f32 -> Bt hi/lo [256][KPAD] bf16 (transposed, zero-padded)
__global__ __launch_bounds__(256) void cvtB_kernel(const float* __restrict__ B,
                                                   ushort* __restrict__ thi,
                                                   ushort* __restrict__ tlo) {
  int i = blockIdx.x * 256 + threadIdx.x;   // 0..65535
  int nn = i >> 8;
  int k4 = (i & 255) << 2;
  ushort4 h, l;
#pragma unroll
  for (int j = 0; j < 4; ++j) {
    int k = k4 + j;
    float v = (k < IN_FEAT) ? B[(size_t)k * FOUT + nn] : 0.f;
    ushort hh, ll;
    bf16split(v, hh, ll);
    ((ushort*)&h)[j] = hh;
    ((ushort*)&l)[j] = ll;
  }
  *(ushort4*)(thi + (size_t)nn * KPAD + k4) = h;
  *(ushort4*)(tlo + (size_t)nn * KPAD + k4) = l;
}

// ---------------- fused-conversion split-bf16 MFMA GEMM: h1 = x @ W1 ----------------
// A: x[50000][1000] f32 read directly, trunc-split to hi/lo bf16 in-register.
// B: Bt hi/lo [256][KPAD] bf16 via global_load_lds (pre-swizzled source).
// BM=128 rows x BN=128 cols per block, BK=64, 4 waves (64x64 wave tile).
__global__ __launch_bounds__(256, 2) void gemm_fused_kernel(
    const float* __restrict__ X,
    const ushort* __restrict__ Bhi, const ushort* __restrict__ Blo,
    float* __restrict__ C) {
  __shared__ ushort lAhi[128 * 64];
  __shared__ ushort lAlo[128 * 64];
  __shared__ ushort lBhi[128 * 64];
  __shared__ ushort lBlo[128 * 64];

  // bijective XCD swizzle (m204)
  const int orig = blockIdx.x;
  const int q = GEMM_NWG >> 3, r = GEMM_NWG & 7;
  const int xcd = orig & 7, idx = orig >> 3;
  const int lin = (xcd < r) ? xcd * (q + 1) + idx : r * (q + 1) + (xcd - r) * q + idx;
  const int brow = (lin >> 1) * 128;
  const int bcol = (lin & 1) * 128;

  const int t = threadIdx.x;
  const int lane = t & 63, wid = t >> 6;
  const int wr = wid >> 1, wc = wid & 1;
  const int fr = lane & 15, g = lane >> 4;

  // per-thread A chunks: c = i*256+t, row=c>>3, kc8=c&7 (8-float k-chunk),
  // global k pre-swizzled: kc_src = kc8 ^ (row&7)  -> LDS written LINEARLY,
  // frag-read applies the XOR (both-sides pair, rule #21).
  float4 areg[8];

  auto loadA = [&](int ks) {
#pragma unroll
    for (int i = 0; i < 4; ++i) {
      const int c = i * 256 + t;
      const int row = c >> 3, kc8 = c & 7;
      const int ksrc = kc8 ^ (row & 7);
      const int rowg = brow + row;
      const int kb = ks * 64 + ksrc * 8;
      if (rowg < N_NODES && kb < IN_FEAT) {
        const float* p = X + (size_t)rowg * IN_FEAT + kb;
        areg[2 * i] = *(const float4*)p;
        areg[2 * i + 1] = *(const float4*)(p + 4);
      } else {
        areg[2 * i] = make_float4(0.f, 0.f, 0.f, 0.f);
        areg[2 * i + 1] = make_float4(0.f, 0.f, 0.f, 0.f);
      }
    }
  };

  auto stageB = [&](int ks) {
    const int k0b = ks * 128;
#pragma unroll
    for (int i = 0; i < 4; ++i) {
      int u = i * 256 + t;
      int row = u >> 3;
      int inner = (u & 7) * 16;
      int soff = inner ^ ((row & 7) << 4);
      size_t boff = (size_t)(bcol + row) * (KPAD * 2) + k0b + soff;
      int loff = u * 16;
      gload_lds16((const char*)Bhi + boff, (char*)lBhi + loff);
      gload_lds16((const char*)Blo + boff, (char*)lBlo + loff);
    }
  };

  f32x4 acc[4][4];
  const f32x4 z4 = {0.f, 0.f, 0.f, 0.f};
#pragma unroll
  for (int m = 0; m < 4; ++m)
#pragma unroll
    for (int n = 0; n < 4; ++n) acc[m][n] = z4;

  loadA(0);
  const int NK = KPAD / 64;  // 16
  for (int ks = 0; ks < NK; ++ks) {
    // trunc-split current A regs -> hi/lo packed
    union U8 { uint4 q; ushort us[8]; };
    U8 hiv[4], lov[4];
#pragma unroll
    for (int i = 0; i < 4; ++i) {
      const float* vv = (const float*)&areg[2 * i];
#pragma unroll
      for (int j = 0; j < 8; ++j) {
        unsigned u = __float_as_uint(vv[j]);
        ushort h = (ushort)(u >> 16);
        float hf = __uint_as_float(u & 0xFFFF0000u);
        float d = vv[j] - hf;
        ushort l = (ushort)(__float_as_uint(d) >> 16);
        hiv[i].us[j] = h;
        lov[i].us[j] = l;
      }
    }
    __syncthreads();  // (a) all waves done reading prev tile
#pragma unroll
    for (int i = 0; i < 4; ++i) {
      const int c = i * 256 + t;
      *(uint4*)((char*)lAhi + c * 16) = hiv[i].q;
      *(uint4*)((char*)lAlo + c * 16) = lov[i].q;
    }
    stageB(ks);
    __syncthreads();  // (b) drains ds_writes + B gload_lds; tile published
    if (ks + 1 < NK) loadA(ks + 1);  // in flight during MFMA phase
#pragma unroll
    for (int h = 0; h < 2; ++h) {
      bf16x8 ah[4], al[4], bh[4], bl[4];
#pragma unroll
      for (int m = 0; m < 4; ++m) {
        int row = wr * 64 + m * 16 + fr;
        int off = row * 128 + ((h * 64 + g * 16) ^ ((row & 7) << 4));
        ah[m] = *(const bf16x8*)((const char*)lAhi + off);
        al[m] = *(const bf16x8*)((const char*)lAlo + off);
      }
#pragma unroll
      for (int n = 0; n < 4; ++n) {
        int row = wc * 64 + n * 16 + fr;
        int off = row * 128 + ((h * 64 + g * 16) ^ ((row & 7) << 4));
        bh[n] = *(const bf16x8*)((const char*)lBhi + off);
        bl[n] = *(const bf16x8*)((const char*)lBlo + off);
      }
#pragma unroll
      for (int m = 0; m < 4; ++m)
#pragma unroll
        for (int n = 0; n < 4; ++n) {
          acc[m][n] = __builtin_amdgcn_mfma_f32_16x16x32_bf16(ah[m], bh[n], acc[m][n], 0, 0, 0);
          acc[m][n] = __builtin_amdgcn_mfma_f32_16x16x32_bf16(ah[m], bl[n], acc[m][n], 0, 0, 0);
          acc[m][n] = __builtin_amdgcn_mfma_f32_16x16x32_bf16(al[m], bh[n], acc[m][n], 0, 0, 0);
        }
    }
  }

  // C/D layout: col = lane&15, row = (lane>>4)*4 + reg  [m89-verified]
#pragma unroll
  for (int m = 0; m < 4; ++m) {
    int growbase = brow + wr * 64 + m * 16 + g * 4;
#pragma unroll
    for (int n = 0; n < 4; ++n) {
      int gcol = bcol + wc * 64 + n * 16 + fr;
#pragma unroll
      for (int rr = 0; rr < 4; ++rr) {
        int grow = growbase + rr;
        if (grow < N_NODES) C[(size_t)grow * FOUT + gcol] = acc[m][n][rr];
      }
    }
  }
}

// ---------------- attention logits per node ----------------
__global__ __launch_bounds__(64) void att1_kernel(const float* __restrict__ h1,
                                                  const float* __restrict__ as,
                                                  const float* __restrict__ ad,
                                                  float* __restrict__ asrc,
                                                  float* __restrict__ adst) {
  const int n = blockIdx.x;
  const int lane = threadIdx.x;
  const float* hr = h1 + (size_t)n * FOUT;
  float4 hv = *(const float4*)(hr + 4 * lane);
  float4 sv = *(const float4*)(as + 4 * lane);
  float4 dv = *(const float4*)(ad + 4 * lane);
  float ps = hv.x * sv.x + hv.y * sv.y + hv.z * sv.z + hv.w * sv.w;
  float pd = hv.x * dv.x + hv.y * dv.y + hv.z * dv.z + hv.w * dv.w;
#pragma unroll
  for (int off = 16; off > 0; off >>= 1) {  // reduce within each 32-lane half
    ps += __shfl_xor(ps, off, 64);
    pd += __shfl_xor(pd, off, 64);
  }
  if ((lane & 31) == 0) {
    int hh = lane >> 5;
    asrc[2 * n + hh] = ps;
    adst[2 * n + hh] = pd;
  }
}

// ---------------- layer-1 agg: wave-parallel softmax + gather, fused relu+W2 -> z ----------------
__global__ __launch_bounds__(64) void agg1_kernel(
    const float* __restrict__ h1, const float* __restrict__ asrc,
    const float* __restrict__ adst, const int* __restrict__ row_start,
    const int* __restrict__ csr_src, const float* __restrict__ b1,
    const float* __restrict__ W2, float* __restrict__ z) {
  const int n = blockIdx.x;
  const int lane = threadIdx.x;
  const bool head0 = lane < 32;
  const float ad0 = adst[2 * n], ad1 = adst[2 * n + 1];
  const int jb = row_start[n], je = row_start[n + 1];
  float ax = 0.f, ay = 0.f, az = 0.f, aw = 0.f;
  float m0 = -INFINITY, m1 = -INFINITY, s0 = 0.f, s1 = 0.f;

  for (int base = jb; base < je; base += 64) {
    int cnt = je - base;
    if (cnt > 64) cnt = 64;
    const bool act = lane < cnt;
    const int sr = csr_src[base + (act ? lane : 0)];
    float e0 = -INFINITY, e1 = -INFINITY;
    if (act) {
      e0 = lrelu(asrc[2 * sr] + ad0);
      e1 = lrelu(asrc[2 * sr + 1] + ad1);
    }
    float c0 = e0, c1 = e1;
#pragma unroll
    for (int off = 32; off > 0; off >>= 1) {
      c0 = fmaxf(c0, __shfl_xor(c0, off, 64));
      c1 = fmaxf(c1, __shfl_xor(c1, off, 64));
    }
    const float m0n = fmaxf(m0, c0), m1n = fmaxf(m1, c1);
    const float f0 = __expf(m0 - m0n), f1 = __expf(m1 - m1n);  // exp(-inf)=0 first chunk
    const float p0 = act ? __expf(e0 - m0n) : 0.f;
    const float p1 = act ? __expf(e1 - m1n) : 0.f;
    float t0 = p0, t1 = p1;
#pragma unroll
    for (int off = 32; off > 0; off >>= 1) {
      t0 += __shfl_xor(t0, off, 64);
      t1 += __shfl_xor(t1, off, 64);
    }
    s0 = s0 * f0 + t0;
    s1 = s1 * f1 + t1;
    m0 = m0n;
    m1 = m1n;
    const float f = head0 ? f0 : f1;
    ax *= f; ay *= f; az *= f; aw *= f;
    for (int j = 0; j < cnt; ++j) {
      const int srj = __shfl(sr, j, 64);
      const float pj0 = __shfl(p0, j, 64);
      const float pj1 = __shfl(p1, j, 64);
      const float pj = head0 ? pj0 : pj1;
      float4 hv = *(const float4*)(h1 + (size_t)srj * FOUT + 4 * lane);
      ax = fmaf(pj, hv.x, ax);
      ay = fmaf(pj, hv.y, ay);
      az = fmaf(pj, hv.z, az);
      aw = fmaf(pj, hv.w, aw);
    }
  }
  const float inv = head0 ? 1.f / (s0 + EPS) : 1.f / (s1 + EPS);
  float4 bv = *(const float4*)(b1 + 4 * lane);
  float4 wv = *(const float4*)(W2 + 4 * lane);
  float r0 = fmaxf(fmaf(ax, inv, bv.x), 0.f);
  float r1 = fmaxf(fmaf(ay, inv, bv.y), 0.f);
  float r2 = fmaxf(fmaf(az, inv, bv.z), 0.f);
  float r3 = fmaxf(fmaf(aw, inv, bv.w), 0.f);
  float part = r0 * wv.x + r1 * wv.y + r2 * wv.z + r3 * wv.w;
#pragma unroll
  for (int off = 32; off > 0; off >>= 1) part += __shfl_xor(part, off, 64);
  if (lane == 0) z[n] = part;
}

// ---------------- layer-2 GAT (scalar features), wave-parallel ----------------
__global__ __launch_bounds__(64) void agg2_kernel(
    const float* __restrict__ z, const int* __restrict__ row_start,
    const int* __restrict__ csr_src, const float* __restrict__ as2p,
    const float* __restrict__ ad2p, const float* __restrict__ b2p,
    float* __restrict__ out2) {
  const int n = blockIdx.x;
  const int lane = threadIdx.x;
  const float as2 = as2p[0], ad2 = ad2p[0], b2 = b2p[0];
  const float adz = z[n] * ad2;
  const int jb = row_start[n], je = row_start[n + 1];
  float m = -INFINITY, s = 0.f, num = 0.f;
  for (int base = jb; base < je; base += 64) {
    int cnt = je - base;
    if (cnt > 64) cnt = 64;
    const bool act = lane < cnt;
    const int sr = csr_src[base + (act ? lane : 0)];
    const float zs = act ? z[sr] : 0.f;
    const float e = act ? lrelu(zs * as2 + adz) : -INFINITY;
    float c = e;
#pragma unroll
    for (int off = 32; off > 0; off >>= 1) c = fmaxf(c, __shfl_xor(c, off, 64));
    const float mn = fmaxf(m, c);
    const float f = __expf(m - mn);
    const float p = act ? __expf(e - mn) : 0.f;
    float tp = p, tz = p * zs;
#pragma unroll
    for (int off = 32; off > 0; off >>= 1) {
      tp += __shfl_xor(tp, off, 64);
      tz += __shfl_xor(tz, off, 64);
    }
    s = s * f + tp;
    num = num * f + tz;
    m = mn;
  }
  if (lane == 0) out2[n] = num / (s + EPS) + b2;
}

__global__ void readout_kernel(const float* __restrict__ out2, const int* __restrict__ ridx,
                               float* __restrict__ out, int n) {
  int i = blockIdx.x * blockDim.x + threadIdx.x;
  if (i < n) out[i] = out2[ridx[i]];
}

extern "C" void kernel_launch(void* const* d_in, const int* in_sizes, int n_in,
                              void* d_out, int out_size, void* d_ws, size_t ws_size,
                              hipStream_t stream) {
  const float* x   = (const float*)d_in[0];
  const int* ei    = (const int*)d_in[1];
  const int* ridx  = (const int*)d_in[2];
  const float* W1  = (const float*)d_in[3];
  const float* as1 = (const float*)d_in[4];
  const float* ad1 = (const float*)d_in[5];
  const float* b1  = (const float*)d_in[6];
  const float* W2  = (const float*)d_in[7];
  const float* as2 = (const float*)d_in[8];
  const float* ad2 = (const float*)d_in[9];
  const float* b2  = (const float*)d_in[10];
  float* out = (float*)d_out;

  char* ws = (char*)d_ws;
  size_t off = 0;
  auto alloc = [&](size_t bytes) -> void* {
    void* p = ws + off;
    off += (bytes + 255) & ~(size_t)255;
    return p;
  };
  float* h1   = (float*)alloc((size_t)N_NODES * FOUT * 4);
  float* asrc = (float*)alloc((size_t)N_NODES * 2 * 4);
  float* adst = (float*)alloc((size_t)N_NODES * 2 * 4);
  float* z    = (float*)alloc((size_t)N_NODES * 4);
  float* out2 = (float*)alloc((size_t)N_NODES * 4);
  int* counts = (int*)alloc((size_t)N_NODES * 4);
  int* rowst  = (int*)alloc((size_t)(N_NODES + 1) * 4);
  int* cursor = (int*)alloc((size_t)N_NODES * 4);
  int* csr    = (int*)alloc((size_t)N_EDGES * 4);
  int* iscan  = (int*)alloc((size_t)N_NODES * 4);
  int* bsum   = (int*)alloc(64 * 4);
  int* boff   = (int*)alloc(64 * 4);
  ushort* Bhi = (ushort*)alloc((size_t)FOUT * KPAD * 2);
  ushort* Blo = (ushort*)alloc((size_t)FOUT * KPAD * 2);

  const int* src = ei;
  const int* dst = ei + N_EDGES;
  const int nblk = (N_NODES + 1023) / 1024;  // 49

  hipMemsetAsync(counts, 0, (size_t)N_NODES * 4, stream);
  hist_kernel<<<(N_EDGES + 255) / 256, 256, 0, stream>>>(dst, counts);
  scan1_kernel<<<nblk, 1024, 0, stream>>>(counts, iscan, bsum);
  scan2_kernel<<<1, 64, 0, stream>>>(bsum, boff, rowst, nblk);
  scan3_kernel<<<(N_NODES + 255) / 256, 256, 0, stream>>>(iscan, counts, boff, rowst, cursor);
  scatter_kernel<<<(N_EDGES + 255) / 256, 256, 0, stream>>>(src, dst, cursor, csr);

  cvtB_kernel<<<256, 256, 0, stream>>>(W1, Bhi, Blo);
  gemm_fused_kernel<<<GEMM_NWG, 256, 0, stream>>>(x, Bhi, Blo, h1);

  att1_kernel<<<N_NODES, 64, 0, stream>>>(h1, as1, ad1, asrc, adst);
  agg1_kernel<<<N_NODES, 64, 0, stream>>>(h1, asrc, adst, rowst, csr, b1, W2, z);
  agg2_kernel<<<N_NODES, 64, 0, stream>>>(z, rowst, csr, as2, ad2, b2, out2);
  readout_kernel<<<4, 256, 0, stream>>>(out2, ridx, out, out_size);
}